// Round 15
// baseline (139.090 us; speedup 1.0000x reference)
//
#include <hip/hip_runtime.h>
#include <hip/hip_bf16.h>
#include <math.h>

#define NN     8192
#define NIN    64
#define NH     128
#define MAXD   128
#define NTRAIN 4096
#define NSAMP  8192
#define RPB    4      // rows per scan block (one contiguous 128 KB slab)
#define ECAP   1024   // per-block column-edge staging capacity (expect ~64)
#define NW     (NN/32)   // bitmap words per row = 256
#define JSPLIT 16
#define JSL    (NN/JSPLIT)     // 512 cols per j-slice
#define WSL    (JSL/32)        // 16 bitmap words per slice

typedef __attribute__((ext_vector_type(8))) short short8;
typedef __attribute__((ext_vector_type(4))) float f32x4;

__device__ __forceinline__ float dot4(float4 a, float4 b) {
    return a.x*b.x + a.y*b.y + a.z*b.z + a.w*b.w;
}

// K1 (fused, row-tiled): weights in registers, seq/h/xa in LDS.
// Zero-inits cntc, samp_sum, out[0].
__global__ __launch_bounds__(256) void k_lin_fused(
    const float* __restrict__ seq1, const float* __restrict__ W_stru,
    const float* __restrict__ b_stru, const float* __restrict__ W_a1,
    const float* __restrict__ b_a1, const float* __restrict__ W_gat,
    const float* __restrict__ att_src, const float* __restrict__ att_dst,
    const float* __restrict__ W_a2, const float* __restrict__ b_a2,
    float* __restrict__ hp, float* __restrict__ a_s, float* __restrict__ a_d,
    float* __restrict__ attr_err, int* __restrict__ cntc,
    float* __restrict__ samp_sum, float* __restrict__ out)
{
    __shared__ float s_seq[16][NIN];   // 4 KB
    __shared__ float h_lds[16][NH];    // 8 KB
    __shared__ float x_lds[16][NH];    // 8 KB
    int t = threadIdx.x;
    int r0 = blockIdx.x * 16;

    int gid = blockIdx.x * 256 + t;
    if (gid < NN) { cntc[gid] = 0; samp_sum[gid] = 0.f; }
    if (gid == 0) out[0] = 0.f;

    ((float4*)&s_seq[0][0])[t] = ((const float4*)(seq1 + (size_t)r0 * NIN))[t];

    int mat = t >> 7, hd = t & 127;
    const float4* Wrow1 = (const float4*)((mat ? W_a1 : W_stru) + (size_t)hd * NIN);
    float4 w1[16];
#pragma unroll
    for (int k = 0; k < 16; ++k) w1[k] = Wrow1[k];
    float b1 = (mat ? b_a1 : b_stru)[hd];
    float* dstl = mat ? &x_lds[0][0] : &h_lds[0][0];
    __syncthreads();

    for (int rl = 0; rl < 16; ++rl) {
        const float4* s4 = (const float4*)&s_seq[rl][0];
        float acc = 0.f;
#pragma unroll
        for (int k = 0; k < 16; ++k) acc += dot4(s4[k], w1[k]);
        dstl[rl * NH + hd] = fmaxf(acc + b1, 0.f);
    }
    __syncthreads();

    if (t < 128) {
        int d = t & 63;
        const float4* Wrow2 = (const float4*)((t < 64 ? W_gat : W_a2) + (size_t)d * NH);
        float4 w2[32];                 // 128 VGPR
#pragma unroll
        for (int k = 0; k < 32; ++k) w2[k] = Wrow2[k];
        float b2   = (t < 64) ? 0.f : b_a2[d];
        float as_c = att_src[d], ad_c = att_dst[d];
        const float* vbase = (t < 64) ? &h_lds[0][0] : &x_lds[0][0];
        for (int rl = 0; rl < 16; ++rl) {
            const float4* v4 = (const float4*)(vbase + rl * NH);
            float acc = 0.f;
#pragma unroll
            for (int k = 0; k < 32; ++k) acc += dot4(v4[k], w2[k]);
            int r = r0 + rl;
            if (t < 64) {
                hp[(size_t)r * NIN + d] = acc;
                float asv = acc * as_c, adv = acc * ad_c;
#pragma unroll
                for (int o = 32; o > 0; o >>= 1) {
                    asv += __shfl_xor(asv, o);
                    adv += __shfl_xor(adv, o);
                }
                if (d == 0) { a_s[r] = asv; a_d[r] = adv; }
            } else {
                float diff = s_seq[rl][d] - (acc + b2);
                float de = diff * diff;
#pragma unroll
                for (int o = 32; o > 0; o >>= 1) de += __shfl_xor(de, o);
                if (d == 0) attr_err[r] = sqrtf(de);
            }
        }
    }
}

// K2: streaming scan; block owns 4 complete rows (contiguous 128 KB slab).
// MLP version: all 32 per-thread uint4 loads issued as two 16-deep register
// batches BEFORE any processing (512 B in flight per lane, 4x the old 128 B)
// -- the kernel is HBM-latency-bound, so throughput ~ bytes-in-flight.
// Bitmap in LDS (atomicOr); column edges staged in LDS, drained once.
__global__ __launch_bounds__(256) void k_scan(const float* __restrict__ adj,
                       unsigned* __restrict__ bitmap,
                       int* __restrict__ cntc, int* __restrict__ listc)
{
    __shared__ unsigned s_bm[RPB][NW];   // 4 KB
    __shared__ int s_ne;
    __shared__ int s_ej[ECAP], s_ei[ECAP];
    int t = threadIdx.x;
    int r0 = blockIdx.x * RPB;
    const uint4* base = (const uint4*)adj + (size_t)r0 * (NN/4) + t;

    for (int w = t; w < RPB * NW; w += 256) ((unsigned*)s_bm)[w] = 0u;
    if (t == 0) s_ne = 0;
    __syncthreads();

    uint4 va[16], vb[16];
#pragma unroll
    for (int u = 0; u < 16; ++u) va[u] = base[(size_t)u * 256];
#pragma unroll
    for (int u = 0; u < 16; ++u) vb[u] = base[(size_t)(16 + u) * 256];

    auto process = [&](const uint4* v, int fbase) {
#pragma unroll
        for (int u = 0; u < 16; ++u) {
            if (v[u].x | v[u].y | v[u].z | v[u].w) {
                int f  = fbase + u * 256 + t;      // uint4 index within slab
                int rl = f >> 11;                  // f / (NN/4)
                int c4 = f & 2047;
                unsigned vals[4] = {v[u].x, v[u].y, v[u].z, v[u].w};
#pragma unroll
                for (int e = 0; e < 4; ++e) {
                    if (vals[e]) {
                        int j = c4 * 4 + e;
                        atomicOr(&s_bm[rl][j >> 5], 1u << (j & 31));
                        int q = atomicAdd(&s_ne, 1);
                        if (q < ECAP) { s_ej[q] = j; s_ei[q] = r0 + rl; }
                    }
                }
            }
        }
    };
    process(va, 0);
    process(vb, 16 * 256);
    __syncthreads();

    uint4* bmo = (uint4*)(bitmap + (size_t)r0 * NW);
    for (int w = t; w < (RPB * NW) / 4; w += 256)
        bmo[w] = ((uint4*)s_bm)[w];
    int ne = s_ne; if (ne > ECAP) ne = ECAP;
    for (int e = t; e < ne; e += 256) {
        int j = s_ej[e];
        int q = atomicAdd(&cntc[j], 1);
        if (q < MAXD) listc[(size_t)j * MAXD + q] = s_ei[e];
    }
}

// K3: per-column softmax + weighted feature sum over sparse source list.
__global__ void k_softmax_col(const float* __restrict__ hp, const float* __restrict__ a_s,
                              const float* __restrict__ a_d, const int* __restrict__ cntc,
                              const int* __restrict__ listc, const float* __restrict__ b_gat,
                              __hip_bfloat16* __restrict__ embb)
{
    int j = blockIdx.x * 4 + (threadIdx.x >> 6);
    int lane = threadIdx.x & 63;
    float adv = a_d[j];
    float x = a_s[j] + adv;
    float e = x > 0.f ? x : 0.2f * x;
    float w = __expf(e);
    float den = w;
    float acc = w * hp[(size_t)j*NIN + lane];
    int c = cntc[j]; if (c > MAXD) c = MAXD;
    for (int t = 0; t < c; ++t) {
        int i = listc[(size_t)j*MAXD + t];
        float xi = a_s[i] + adv;
        float ei = xi > 0.f ? xi : 0.2f * xi;
        float wi = __expf(ei);
        den += wi;
        acc += wi * hp[(size_t)i*NIN + lane];
    }
    float v = acc / den + b_gat[lane];
    embb[(size_t)j*NIN + lane] = __float2bfloat16(v);
}

// K4: partial stru-err. Grid (NSAMP/128, JSPLIT). Block: 128 samples x
// 512-col j-slice. Each wave owns 32 samples (2 A-frag sets -> 4 MFMA per
// B-tile). Bitmap slice in LDS. Partials -> samp_sum via spread atomics.
__global__ __launch_bounds__(256) void k_score_part(const __hip_bfloat16* __restrict__ embb,
                       const unsigned* __restrict__ bitmap,
                       const int* __restrict__ idx_tr, const int* __restrict__ idx_te,
                       float* __restrict__ samp_sum)
{
    __shared__ int s_rows[128];
    __shared__ unsigned s_bm[128][WSL + 1];   // pad: conflict-free
    int t = threadIdx.x;
    int r0 = blockIdx.x * 128;
    int jbase = blockIdx.y * JSL;
    int wwbase = blockIdx.y * WSL;
    if (t < 128) {
        int r = r0 + t;
        s_rows[t] = r < NTRAIN ? idx_tr[r] : idx_te[r - NTRAIN];
    }
    __syncthreads();
    for (int idx = t; idx < 128 * WSL; idx += 256) {
        int rl = idx / WSL, w = idx % WSL;
        s_bm[rl][w] = bitmap[(size_t)s_rows[rl] * NW + wwbase + w];
    }
    int wv = t >> 6, l = t & 63;
    int lr = l & 15, lk = l >> 4;
    const short8* ar0 = (const short8*)(embb + (size_t)s_rows[wv * 32 + lr] * NIN);
    const short8* ar1 = (const short8*)(embb + (size_t)s_rows[wv * 32 + 16 + lr] * NIN);
    short8 a00 = ar0[lk], a01 = ar0[lk + 4];
    short8 a10 = ar1[lk], a11 = ar1[lk + 4];
    __syncthreads();

    f32x4 racc0 = {0.f, 0.f, 0.f, 0.f};
    f32x4 racc1 = {0.f, 0.f, 0.f, 0.f};
    for (int nt = 0; nt < JSL / 16; ++nt) {          // 32 tiles
        int jl = nt * 16 + lr;                        // local col
        const short8* bptr = (const short8*)(embb + (size_t)(jbase + jl) * NIN);
        short8 b0 = bptr[lk], b1 = bptr[lk + 4];
        f32x4 c0 = {0.f, 0.f, 0.f, 0.f};
        f32x4 c1 = {0.f, 0.f, 0.f, 0.f};
        c0 = __builtin_amdgcn_mfma_f32_16x16x32_bf16(a00, b0, c0, 0, 0, 0);
        c0 = __builtin_amdgcn_mfma_f32_16x16x32_bf16(a01, b1, c0, 0, 0, 0);
        c1 = __builtin_amdgcn_mfma_f32_16x16x32_bf16(a10, b0, c1, 0, 0, 0);
        c1 = __builtin_amdgcn_mfma_f32_16x16x32_bf16(a11, b1, c1, 0, 0, 0);
        int ww = jl >> 5, wb = jl & 31;
#pragma unroll
        for (int q = 0; q < 4; ++q) {
            int row0 = wv * 32 + lk * 4 + q;
            float bb0  = (float)((s_bm[row0][ww] >> wb) & 1u);
            float sig0 = __builtin_amdgcn_rcpf(1.f + __expf(-c0[q]));
            float d0   = bb0 - sig0;
            racc0[q] += d0 * d0;
            float bb1  = (float)((s_bm[row0 + 16][ww] >> wb) & 1u);
            float sig1 = __builtin_amdgcn_rcpf(1.f + __expf(-c1[q]));
            float d1   = bb1 - sig1;
            racc1[q] += d1 * d1;
        }
    }
#pragma unroll
    for (int off = 1; off < 16; off <<= 1) {
#pragma unroll
        for (int q = 0; q < 4; ++q) {
            racc0[q] += __shfl_xor(racc0[q], off);
            racc1[q] += __shfl_xor(racc1[q], off);
        }
    }
    if (lr == 0) {
#pragma unroll
        for (int q = 0; q < 4; ++q) {
            atomicAdd(&samp_sum[r0 + wv * 32 + lk * 4 + q],      racc0[q]);
            atomicAdd(&samp_sum[r0 + wv * 32 + 16 + lk * 4 + q], racc1[q]);
        }
    }
}

// K5: final scores. Block-level LDS reduce -> ONE atomicAdd per block.
__global__ __launch_bounds__(256) void k_fin(const float* __restrict__ samp_sum,
                       const float* __restrict__ attr_err,
                       const int* __restrict__ idx_tr, const int* __restrict__ idx_te,
                       float* __restrict__ out)
{
    __shared__ float red[256];
    int t = threadIdx.x;
    int r = blockIdx.x * 256 + t;
    int row = r < NTRAIN ? idx_tr[r] : idx_te[r - NTRAIN];
    float sq = samp_sum[r];
    if (sq < 0.f) sq = 0.f;
    float sc = 0.5f * attr_err[row] + 0.5f * sqrtf(sq);
    float tr = (r < NTRAIN) ? sc : 0.f;
    if (r >= NTRAIN) out[1 + r - NTRAIN] = sc;
    red[t] = tr;
    __syncthreads();
    for (int w = 128; w > 0; w >>= 1) {
        if (t < w) red[t] += red[t + w];
        __syncthreads();
    }
    if (t == 0 && red[0] != 0.f) atomicAdd(out, red[0] * (1.f / NTRAIN));
}

extern "C" void kernel_launch(void* const* d_in, const int* in_sizes, int n_in,
                              void* d_out, int out_size, void* d_ws, size_t ws_size,
                              hipStream_t stream)
{
    const float* seq1    = (const float*)d_in[0];
    const float* adj     = (const float*)d_in[1];
    const int*   idx_tr  = (const int*)d_in[2];
    const int*   idx_te  = (const int*)d_in[3];
    const float* W_stru  = (const float*)d_in[4];
    const float* b_stru  = (const float*)d_in[5];
    const float* W_gat   = (const float*)d_in[6];
    const float* att_src = (const float*)d_in[7];
    const float* att_dst = (const float*)d_in[8];
    const float* b_gat   = (const float*)d_in[9];
    const float* W_a1    = (const float*)d_in[10];
    const float* b_a1    = (const float*)d_in[11];
    const float* W_a2    = (const float*)d_in[12];
    const float* b_a2    = (const float*)d_in[13];
    float* out = (float*)d_out;

    char* ws = (char*)d_ws;
    size_t off = 0;
    auto alloc = [&](size_t bytes) {
        size_t p = off;
        off += (bytes + 255) & ~(size_t)255;
        return p;
    };
    float* hp       = (float*)(ws + alloc((size_t)NN*NIN*4));
    float* a_s      = (float*)(ws + alloc((size_t)NN*4));
    float* a_d      = (float*)(ws + alloc((size_t)NN*4));
    float* attr_err = (float*)(ws + alloc((size_t)NN*4));
    __hip_bfloat16* embb = (__hip_bfloat16*)(ws + alloc((size_t)NN*NIN*2));
    unsigned* bitmap = (unsigned*)(ws + alloc((size_t)NN*NW*4));   // 8 MB
    int*   cntc     = (int*)  (ws + alloc((size_t)NN*4));
    int*   listc    = (int*)  (ws + alloc((size_t)NN*MAXD*4));
    float* samp_sum = (float*)(ws + alloc((size_t)NSAMP*4));

    k_lin_fused<<<NN/16, 256, 0, stream>>>(seq1, W_stru, b_stru, W_a1, b_a1, W_gat,
                                           att_src, att_dst, W_a2, b_a2,
                                           hp, a_s, a_d, attr_err, cntc, samp_sum, out);
    k_scan<<<NN/RPB, 256, 0, stream>>>(adj, bitmap, cntc, listc);
    k_softmax_col<<<NN/4, 256, 0, stream>>>(hp, a_s, a_d, cntc, listc, b_gat, embb);
    k_score_part<<<dim3(NSAMP/128, JSPLIT), 256, 0, stream>>>(embb, bitmap,
                                                              idx_tr, idx_te, samp_sum);
    k_fin<<<NSAMP/256, 256, 0, stream>>>(samp_sum, attr_err, idx_tr, idx_te, out);
}

// Round 16
// 121.821 us; speedup vs baseline: 1.1418x; 1.1418x over previous
//
#include <hip/hip_runtime.h>
#include <hip/hip_bf16.h>
#include <math.h>

#define NN     8192
#define NIN    64
#define NH     128
#define MAXD   128
#define NTRAIN 4096
#define NSAMP  8192
#define RPB    4      // rows per scan block (one contiguous 128 KB slab)
#define ECAP   1024   // per-block column-edge staging capacity (expect ~64)
#define NW     (NN/32)   // bitmap words per row = 256
#define JSPLIT 16
#define JSL    (NN/JSPLIT)     // 512 cols per j-slice
#define WSL    (JSL/32)        // 16 bitmap words per slice
#define LINB   (NN/16)         // 512 lin-role blocks
#define SCANB  (NN/RPB)        // 2048 scan-role blocks

typedef __attribute__((ext_vector_type(8))) short short8;
typedef __attribute__((ext_vector_type(4))) float f32x4;

__device__ __forceinline__ float dot4(float4 a, float4 b) {
    return a.x*b.x + a.y*b.y + a.z*b.z + a.w*b.w;
}

// K0: zero-init (must complete before fused kernel's column-edge atomics).
__global__ void k_init(int* __restrict__ cntc, float* __restrict__ samp_sum,
                       float* __restrict__ out)
{
    int i = blockIdx.x * 256 + threadIdx.x;
    cntc[i] = 0;
    samp_sum[i] = 0.f;
    if (i == 0) out[0] = 0.f;
}

// K1 (heterogeneous): bid < LINB -> lin role (compute-only; weights in
// registers; hides under the scan's memory wall). bid >= LINB -> scan role
// (R14's 8-deep slab scan: LDS bitmap + staged column edges).
// The scan is pinned at ~3.3 TB/s (read-path ceiling; R7/R14/R15 nulls),
// with idle VALU and occupancy-insensitive -> free room for the lin work.
__global__ __launch_bounds__(256) void k_scan_lin(
    const float* __restrict__ adj, unsigned* __restrict__ bitmap,
    int* __restrict__ cntc, int* __restrict__ listc,
    const float* __restrict__ seq1, const float* __restrict__ W_stru,
    const float* __restrict__ b_stru, const float* __restrict__ W_a1,
    const float* __restrict__ b_a1, const float* __restrict__ W_gat,
    const float* __restrict__ att_src, const float* __restrict__ att_dst,
    const float* __restrict__ W_a2, const float* __restrict__ b_a2,
    float* __restrict__ hp, float* __restrict__ a_s, float* __restrict__ a_d,
    float* __restrict__ attr_err)
{
    __shared__ __attribute__((aligned(16))) char smem[20480];
    int t = threadIdx.x;

    if (blockIdx.x < LINB) {
        // ---------------- LIN role ----------------
        float (*s_seq)[NIN] = (float (*)[NIN])smem;            // 4 KB
        float (*h_lds)[NH]  = (float (*)[NH])(smem + 4096);    // 8 KB
        float (*x_lds)[NH]  = (float (*)[NH])(smem + 12288);   // 8 KB
        int r0 = blockIdx.x * 16;

        ((float4*)&s_seq[0][0])[t] = ((const float4*)(seq1 + (size_t)r0 * NIN))[t];

        int mat = t >> 7, hd = t & 127;
        const float4* Wrow1 = (const float4*)((mat ? W_a1 : W_stru) + (size_t)hd * NIN);
        float4 w1[16];
#pragma unroll
        for (int k = 0; k < 16; ++k) w1[k] = Wrow1[k];
        float b1 = (mat ? b_a1 : b_stru)[hd];
        float* dstl = mat ? &x_lds[0][0] : &h_lds[0][0];
        __syncthreads();

        for (int rl = 0; rl < 16; ++rl) {
            const float4* s4 = (const float4*)&s_seq[rl][0];
            float acc = 0.f;
#pragma unroll
            for (int k = 0; k < 16; ++k) acc += dot4(s4[k], w1[k]);
            dstl[rl * NH + hd] = fmaxf(acc + b1, 0.f);
        }
        __syncthreads();

        if (t < 128) {
            int d = t & 63;
            const float4* Wrow2 = (const float4*)((t < 64 ? W_gat : W_a2) + (size_t)d * NH);
            float4 w2[32];                 // 128 VGPR (occupancy hit is free: scan is insensitive)
#pragma unroll
            for (int k = 0; k < 32; ++k) w2[k] = Wrow2[k];
            float b2   = (t < 64) ? 0.f : b_a2[d];
            float as_c = att_src[d], ad_c = att_dst[d];
            const float* vbase = (t < 64) ? &h_lds[0][0] : &x_lds[0][0];
            for (int rl = 0; rl < 16; ++rl) {
                const float4* v4 = (const float4*)(vbase + rl * NH);
                float acc = 0.f;
#pragma unroll
                for (int k = 0; k < 32; ++k) acc += dot4(v4[k], w2[k]);
                int r = r0 + rl;
                if (t < 64) {
                    hp[(size_t)r * NIN + d] = acc;
                    float asv = acc * as_c, adv = acc * ad_c;
#pragma unroll
                    for (int o = 32; o > 0; o >>= 1) {
                        asv += __shfl_xor(asv, o);
                        adv += __shfl_xor(adv, o);
                    }
                    if (d == 0) { a_s[r] = asv; a_d[r] = adv; }
                } else {
                    float diff = s_seq[rl][d] - (acc + b2);
                    float de = diff * diff;
#pragma unroll
                    for (int o = 32; o > 0; o >>= 1) de += __shfl_xor(de, o);
                    if (d == 0) attr_err[r] = sqrtf(de);
                }
            }
        }
    } else {
        // ---------------- SCAN role ----------------
        unsigned (*s_bm)[NW] = (unsigned (*)[NW])smem;          // 4 KB
        int* s_ne = (int*)(smem + 4096);
        int* s_ej = (int*)(smem + 4096 + 16);                   // 4 KB
        int* s_ei = (int*)(smem + 4096 + 16 + ECAP * 4);        // 4 KB
        int r0 = (blockIdx.x - LINB) * RPB;
        const uint4* base = (const uint4*)adj + (size_t)r0 * (NN/4) + t;

        for (int w = t; w < RPB * NW; w += 256) ((unsigned*)s_bm)[w] = 0u;
        if (t == 0) *s_ne = 0;
        __syncthreads();

        for (int it = 0; it < (RPB * (NN/4)) / (256 * 8); ++it) {   // 4 iters
            uint4 v[8];
#pragma unroll
            for (int u = 0; u < 8; ++u)
                v[u] = base[(size_t)(it * 8 + u) * 256];
#pragma unroll
            for (int u = 0; u < 8; ++u) {
                if (v[u].x | v[u].y | v[u].z | v[u].w) {
                    int f  = (it * 8 + u) * 256 + t;
                    int rl = f >> 11;
                    int c4 = f & 2047;
                    unsigned vals[4] = {v[u].x, v[u].y, v[u].z, v[u].w};
#pragma unroll
                    for (int e = 0; e < 4; ++e) {
                        if (vals[e]) {
                            int j = c4 * 4 + e;
                            atomicOr(&s_bm[rl][j >> 5], 1u << (j & 31));
                            int q = atomicAdd(s_ne, 1);
                            if (q < ECAP) { s_ej[q] = j; s_ei[q] = r0 + rl; }
                        }
                    }
                }
            }
        }
        __syncthreads();

        uint4* bmo = (uint4*)(bitmap + (size_t)r0 * NW);
        for (int w = t; w < (RPB * NW) / 4; w += 256)
            bmo[w] = ((uint4*)s_bm)[w];
        int ne = *s_ne; if (ne > ECAP) ne = ECAP;
        for (int e = t; e < ne; e += 256) {
            int j = s_ej[e];
            int q = atomicAdd(&cntc[j], 1);
            if (q < MAXD) listc[(size_t)j * MAXD + q] = s_ei[e];
        }
    }
}

// K3: per-column softmax + weighted feature sum over sparse source list.
__global__ void k_softmax_col(const float* __restrict__ hp, const float* __restrict__ a_s,
                              const float* __restrict__ a_d, const int* __restrict__ cntc,
                              const int* __restrict__ listc, const float* __restrict__ b_gat,
                              __hip_bfloat16* __restrict__ embb)
{
    int j = blockIdx.x * 4 + (threadIdx.x >> 6);
    int lane = threadIdx.x & 63;
    float adv = a_d[j];
    float x = a_s[j] + adv;
    float e = x > 0.f ? x : 0.2f * x;
    float w = __expf(e);
    float den = w;
    float acc = w * hp[(size_t)j*NIN + lane];
    int c = cntc[j]; if (c > MAXD) c = MAXD;
    for (int t = 0; t < c; ++t) {
        int i = listc[(size_t)j*MAXD + t];
        float xi = a_s[i] + adv;
        float ei = xi > 0.f ? xi : 0.2f * xi;
        float wi = __expf(ei);
        den += wi;
        acc += wi * hp[(size_t)i*NIN + lane];
    }
    float v = acc / den + b_gat[lane];
    embb[(size_t)j*NIN + lane] = __float2bfloat16(v);
}

// K4: partial stru-err. Grid (NSAMP/128, JSPLIT). Block: 128 samples x
// 512-col j-slice; wave owns 32 samples (2 A-frag sets). Bitmap slice in
// LDS. Partials -> samp_sum via spread atomics.
__global__ __launch_bounds__(256) void k_score_part(const __hip_bfloat16* __restrict__ embb,
                       const unsigned* __restrict__ bitmap,
                       const int* __restrict__ idx_tr, const int* __restrict__ idx_te,
                       float* __restrict__ samp_sum)
{
    __shared__ int s_rows[128];
    __shared__ unsigned s_bm[128][WSL + 1];   // pad: conflict-free
    int t = threadIdx.x;
    int r0 = blockIdx.x * 128;
    int jbase = blockIdx.y * JSL;
    int wwbase = blockIdx.y * WSL;
    if (t < 128) {
        int r = r0 + t;
        s_rows[t] = r < NTRAIN ? idx_tr[r] : idx_te[r - NTRAIN];
    }
    __syncthreads();
    for (int idx = t; idx < 128 * WSL; idx += 256) {
        int rl = idx / WSL, w = idx % WSL;
        s_bm[rl][w] = bitmap[(size_t)s_rows[rl] * NW + wwbase + w];
    }
    int wv = t >> 6, l = t & 63;
    int lr = l & 15, lk = l >> 4;
    const short8* ar0 = (const short8*)(embb + (size_t)s_rows[wv * 32 + lr] * NIN);
    const short8* ar1 = (const short8*)(embb + (size_t)s_rows[wv * 32 + 16 + lr] * NIN);
    short8 a00 = ar0[lk], a01 = ar0[lk + 4];
    short8 a10 = ar1[lk], a11 = ar1[lk + 4];
    __syncthreads();

    f32x4 racc0 = {0.f, 0.f, 0.f, 0.f};
    f32x4 racc1 = {0.f, 0.f, 0.f, 0.f};
    for (int nt = 0; nt < JSL / 16; ++nt) {          // 32 tiles
        int jl = nt * 16 + lr;                        // local col
        const short8* bptr = (const short8*)(embb + (size_t)(jbase + jl) * NIN);
        short8 b0 = bptr[lk], b1 = bptr[lk + 4];
        f32x4 c0 = {0.f, 0.f, 0.f, 0.f};
        f32x4 c1 = {0.f, 0.f, 0.f, 0.f};
        c0 = __builtin_amdgcn_mfma_f32_16x16x32_bf16(a00, b0, c0, 0, 0, 0);
        c0 = __builtin_amdgcn_mfma_f32_16x16x32_bf16(a01, b1, c0, 0, 0, 0);
        c1 = __builtin_amdgcn_mfma_f32_16x16x32_bf16(a10, b0, c1, 0, 0, 0);
        c1 = __builtin_amdgcn_mfma_f32_16x16x32_bf16(a11, b1, c1, 0, 0, 0);
        int ww = jl >> 5, wb = jl & 31;
#pragma unroll
        for (int q = 0; q < 4; ++q) {
            int row0 = wv * 32 + lk * 4 + q;
            float bb0  = (float)((s_bm[row0][ww] >> wb) & 1u);
            float sig0 = __builtin_amdgcn_rcpf(1.f + __expf(-c0[q]));
            float d0   = bb0 - sig0;
            racc0[q] += d0 * d0;
            float bb1  = (float)((s_bm[row0 + 16][ww] >> wb) & 1u);
            float sig1 = __builtin_amdgcn_rcpf(1.f + __expf(-c1[q]));
            float d1   = bb1 - sig1;
            racc1[q] += d1 * d1;
        }
    }
#pragma unroll
    for (int off = 1; off < 16; off <<= 1) {
#pragma unroll
        for (int q = 0; q < 4; ++q) {
            racc0[q] += __shfl_xor(racc0[q], off);
            racc1[q] += __shfl_xor(racc1[q], off);
        }
    }
    if (lr == 0) {
#pragma unroll
        for (int q = 0; q < 4; ++q) {
            atomicAdd(&samp_sum[r0 + wv * 32 + lk * 4 + q],      racc0[q]);
            atomicAdd(&samp_sum[r0 + wv * 32 + 16 + lk * 4 + q], racc1[q]);
        }
    }
}

// K5: final scores. Block-level LDS reduce -> ONE atomicAdd per block.
__global__ __launch_bounds__(256) void k_fin(const float* __restrict__ samp_sum,
                       const float* __restrict__ attr_err,
                       const int* __restrict__ idx_tr, const int* __restrict__ idx_te,
                       float* __restrict__ out)
{
    __shared__ float red[256];
    int t = threadIdx.x;
    int r = blockIdx.x * 256 + t;
    int row = r < NTRAIN ? idx_tr[r] : idx_te[r - NTRAIN];
    float sq = samp_sum[r];
    if (sq < 0.f) sq = 0.f;
    float sc = 0.5f * attr_err[row] + 0.5f * sqrtf(sq);
    float tr = (r < NTRAIN) ? sc : 0.f;
    if (r >= NTRAIN) out[1 + r - NTRAIN] = sc;
    red[t] = tr;
    __syncthreads();
    for (int w = 128; w > 0; w >>= 1) {
        if (t < w) red[t] += red[t + w];
        __syncthreads();
    }
    if (t == 0 && red[0] != 0.f) atomicAdd(out, red[0] * (1.f / NTRAIN));
}

extern "C" void kernel_launch(void* const* d_in, const int* in_sizes, int n_in,
                              void* d_out, int out_size, void* d_ws, size_t ws_size,
                              hipStream_t stream)
{
    const float* seq1    = (const float*)d_in[0];
    const float* adj     = (const float*)d_in[1];
    const int*   idx_tr  = (const int*)d_in[2];
    const int*   idx_te  = (const int*)d_in[3];
    const float* W_stru  = (const float*)d_in[4];
    const float* b_stru  = (const float*)d_in[5];
    const float* W_gat   = (const float*)d_in[6];
    const float* att_src = (const float*)d_in[7];
    const float* att_dst = (const float*)d_in[8];
    const float* b_gat   = (const float*)d_in[9];
    const float* W_a1    = (const float*)d_in[10];
    const float* b_a1    = (const float*)d_in[11];
    const float* W_a2    = (const float*)d_in[12];
    const float* b_a2    = (const float*)d_in[13];
    float* out = (float*)d_out;

    char* ws = (char*)d_ws;
    size_t off = 0;
    auto alloc = [&](size_t bytes) {
        size_t p = off;
        off += (bytes + 255) & ~(size_t)255;
        return p;
    };
    float* hp       = (float*)(ws + alloc((size_t)NN*NIN*4));
    float* a_s      = (float*)(ws + alloc((size_t)NN*4));
    float* a_d      = (float*)(ws + alloc((size_t)NN*4));
    float* attr_err = (float*)(ws + alloc((size_t)NN*4));
    __hip_bfloat16* embb = (__hip_bfloat16*)(ws + alloc((size_t)NN*NIN*2));
    unsigned* bitmap = (unsigned*)(ws + alloc((size_t)NN*NW*4));   // 8 MB
    int*   cntc     = (int*)  (ws + alloc((size_t)NN*4));
    int*   listc    = (int*)  (ws + alloc((size_t)NN*MAXD*4));
    float* samp_sum = (float*)(ws + alloc((size_t)NSAMP*4));

    k_init<<<NN/256, 256, 0, stream>>>(cntc, samp_sum, out);
    k_scan_lin<<<LINB + SCANB, 256, 0, stream>>>(adj, bitmap, cntc, listc,
                                                 seq1, W_stru, b_stru, W_a1, b_a1, W_gat,
                                                 att_src, att_dst, W_a2, b_a2,
                                                 hp, a_s, a_d, attr_err);
    k_softmax_col<<<NN/4, 256, 0, stream>>>(hp, a_s, a_d, cntc, listc, b_gat, embb);
    k_score_part<<<dim3(NSAMP/128, JSPLIT), 256, 0, stream>>>(embb, bitmap,
                                                              idx_tr, idx_te, samp_sum);
    k_fin<<<NSAMP/256, 256, 0, stream>>>(samp_sum, attr_err, idx_tr, idx_te, out);
}